// Round 9
// baseline (1470.266 us; speedup 1.0000x reference)
//
#include <hip/hip_runtime.h>

#define IN_CH 32
#define OUT_CH 128
#define BSHIFT 7
#define BW 128          // nodes per bucket
#define NB_P 1024       // >= ceil(100000/128)=782
#define PCHUNK 2048     // edges per partition block
#define ACH 4096        // edges per k_agg sort-chunk (== slab cap: single pass)

// ---------------------------------------------------------------------------
// A: init per-bucket slab cursors: gcursor[b] = b*cap.
// ---------------------------------------------------------------------------
__global__ __launch_bounds__(512) void k_init(int* __restrict__ gcursor, int cap) {
  int i = blockIdx.x * 512 + threadIdx.x;
  if (i < NB_P) gcursor[i] = i * cap;
}

// ---------------------------------------------------------------------------
// C: partition with LDS reorder + single-wave shfl_up scan (R8-proven)
// ---------------------------------------------------------------------------
__global__ __launch_bounds__(256) void k_partition(const int* __restrict__ src,
                                                   const int* __restrict__ dst,
                                                   int* __restrict__ gcursor,
                                                   unsigned* __restrict__ part,
                                                   int E) {
  __shared__ int cnt[NB_P];
  __shared__ int lbase[NB_P];
  __shared__ int cur[NB_P];
  __shared__ int gbase[NB_P];
  __shared__ int ssum[256];
  __shared__ unsigned sval[PCHUNK];
  __shared__ int sadr[PCHUNK];
  const int t = threadIdx.x;
  const int base = blockIdx.x * PCHUNK;
  const int m = min(PCHUNK, E - base);
  for (int i = t; i < NB_P; i += 256) cnt[i] = 0;
  __syncthreads();
  int dl[8], sl[8];
#pragma unroll
  for (int u = 0; u < 8; ++u) {
    int i = t + 256 * u;
    dl[u] = -1;
    if (i < m) {
      dl[u] = dst[base + i];
      sl[u] = src[base + i];
      atomicAdd(&cnt[dl[u] >> BSHIFT], 1);
    }
  }
  __syncthreads();
  const int b4 = t * 4;
  int c0 = cnt[b4], c1 = cnt[b4 + 1], c2 = cnt[b4 + 2], c3 = cnt[b4 + 3];
  ssum[t] = c0 + c1 + c2 + c3;
  __syncthreads();
  // single-wave exclusive scan of the 256 per-thread sums (4 entries/lane)
  if (t < 64) {
    int s0 = ssum[4 * t], s1 = ssum[4 * t + 1];
    int s2 = ssum[4 * t + 2], s3 = ssum[4 * t + 3];
    int tot = s0 + s1 + s2 + s3;
    int inc = tot;
#pragma unroll
    for (int o = 1; o < 64; o <<= 1) {
      int a = __shfl_up(inc, o);
      if (t >= o) inc += a;
    }
    int excl = inc - tot;
    ssum[4 * t]     = excl;
    ssum[4 * t + 1] = excl + s0;
    ssum[4 * t + 2] = excl + s0 + s1;
    ssum[4 * t + 3] = excl + s0 + s1 + s2;
  }
  __syncthreads();
  int run = ssum[t];
  lbase[b4] = run; cur[b4] = run; run += c0;
  lbase[b4 + 1] = run; cur[b4 + 1] = run; run += c1;
  lbase[b4 + 2] = run; cur[b4 + 2] = run; run += c2;
  lbase[b4 + 3] = run; cur[b4 + 3] = run;
  __syncthreads();
  for (int i = t; i < NB_P; i += 256)
    gbase[i] = cnt[i] ? atomicAdd(&gcursor[i], cnt[i]) : 0;
  __syncthreads();
#pragma unroll
  for (int u = 0; u < 8; ++u) {
    if (dl[u] >= 0) {
      int b = dl[u] >> BSHIFT;
      int p = atomicAdd(&cur[b], 1);
      sval[p] = ((unsigned)sl[u] << BSHIFT) | (unsigned)(dl[u] & (BW - 1));
      sadr[p] = gbase[b] + (p - lbase[b]);
    }
  }
  __syncthreads();
  for (int i = t; i < m; i += 256) part[sadr[i]] = sval[i];
}

// ---------------------------------------------------------------------------
// D: FUSED aggregate + dual-GEMM. Gather phase identical to R8 (proven).
//    Epilogue computes out = x·Wr^T + mean(sacc)·Wl^T + b for the block's
//    own 128 nodes — k_out is gone. LDS 50KB (3 blocks/CU):
//      sacc[16K] | svalu[16K, aliased as xs panel in epilogue] |
//      wsb[16K, two-phase: Wr-transposed (staged at start), then Wl]
//    Subgroup sub owns nodes [8s,8s+8); lane k owns channels [4k,4k+4).
// ---------------------------------------------------------------------------
__global__ __launch_bounds__(512, 6) void k_agg(const float* __restrict__ x,
                                                const unsigned* __restrict__ part,
                                                const int* __restrict__ gcursor,
                                                const float* __restrict__ Wl,
                                                const float* __restrict__ Wr,
                                                const float* __restrict__ bl,
                                                float* __restrict__ out, int n,
                                                int cap) {
  __shared__ float sacc[BW * IN_CH];   // 16 KB, owner-exclusive RMW
  __shared__ float wsb[64 * OUT_CH / 2];  // 16 KB: 32x128 transposed weight panel
  __shared__ unsigned svalu[ACH];      // 16 KB sorted chunk; xs panel in epilogue
  __shared__ int sdeg[BW];
  __shared__ int hcnt[BW];             // sinv (float) in epilogue
  __shared__ int boff[BW + 1];
  __shared__ int cur[BW];
  const int t = threadIdx.x;
  const int sub = t >> 5;   // 16 subgroups of 32 lanes
  const int k = t & 31;     // lane within subgroup
  const int b = blockIdx.x;
  const int node0 = b << BSHIFT;

  // stage Wr-transposed into wsb (wsb[k][c] = Wr[c][k]) — used by GEMM1
  {
    const float4* wr4 = reinterpret_cast<const float4*>(Wr);
#pragma unroll
    for (int r = 0; r < 2; ++r) {
      int i = t + 512 * r;            // [0,1024): c=i>>3, k0=(i&7)*4
      int c = i >> 3;
      int k0 = (i & 7) << 2;
      float4 a = wr4[i];
      wsb[(k0 + 0) * 128 + c] = a.x;
      wsb[(k0 + 1) * 128 + c] = a.y;
      wsb[(k0 + 2) * 128 + c] = a.z;
      wsb[(k0 + 3) * 128 + c] = a.w;
    }
  }
#pragma unroll
  for (int i = 0; i < 8; ++i) sacc[t + 512 * i] = 0.0f;
  if (t < BW) sdeg[t] = 0;
  __syncthreads();

  const int e0 = b * cap;
  const int cn = gcursor[b] - e0;
  const float4* __restrict__ x4 = reinterpret_cast<const float4*>(x);
  const int eg = k >> 3;   // edge slot 0..3
  const int c4 = k & 7;    // float4 channel group 0..7

  for (int base = 0; base < cn; base += ACH) {
    const int m = min(ACH, cn - base);
    if (t < BW) hcnt[t] = 0;
    __syncthreads();
    unsigned ev[8];
#pragma unroll
    for (int u = 0; u < 8; ++u) {
      int i = t + 512 * u;
      ev[u] = 0xFFFFFFFFu;
      if (i < m) {
        ev[u] = part[e0 + base + i];
        atomicAdd(&hcnt[ev[u] & (BW - 1)], 1);
      }
    }
    __syncthreads();
    // single-wave inclusive scan over 128 bins (2 bins/lane, no barriers)
    if (t < 64) {
      int v0 = hcnt[2 * t], v1 = hcnt[2 * t + 1];
      int s = v0 + v1;
#pragma unroll
      for (int o = 1; o < 64; o <<= 1) {
        int a = __shfl_up(s, o);
        if (t >= o) s += a;
      }
      int excl = s - v0 - v1;
      boff[2 * t] = excl;
      cur[2 * t] = excl;
      boff[2 * t + 1] = excl + v0;
      cur[2 * t + 1] = excl + v0;
      sdeg[2 * t] += v0;
      sdeg[2 * t + 1] += v1;
      if (t == 0) boff[BW] = m;
    }
    __syncthreads();
#pragma unroll
    for (int u = 0; u < 8; ++u) {
      if (ev[u] != 0xFFFFFFFFu) {
        int dl = ev[u] & (BW - 1);
        int p = atomicAdd(&cur[dl], 1);
        svalu[p] = ev[u];
      }
    }
    __syncthreads();
    // owner-exclusive segmented reduction: subgroup sub owns bins [8s, 8s+8)
    for (int dd = 0; dd < 8; ++dd) {
      const int d = (sub << 3) + dd;
      int j = boff[d];
      const int je = boff[d + 1];
      float ax = 0.f, ay = 0.f, az = 0.f, aw = 0.f;
      const int je1 = je - 1;
      for (; j < je; j += 16) {
        const int i0 = j + eg;
        const int i1 = j + 4 + eg;
        const int i2 = j + 8 + eg;
        const int i3 = j + 12 + eg;
        const float m0 = (i0 < je) ? 1.f : 0.f;
        const float m1 = (i1 < je) ? 1.f : 0.f;
        const float m2 = (i2 < je) ? 1.f : 0.f;
        const float m3 = (i3 < je) ? 1.f : 0.f;
        float4 v0 = x4[(int)(svalu[min(i0, je1)] >> BSHIFT) * 8 + c4];
        float4 v1 = x4[(int)(svalu[min(i1, je1)] >> BSHIFT) * 8 + c4];
        float4 v2 = x4[(int)(svalu[min(i2, je1)] >> BSHIFT) * 8 + c4];
        float4 v3 = x4[(int)(svalu[min(i3, je1)] >> BSHIFT) * 8 + c4];
        ax += m0 * v0.x + m1 * v1.x + m2 * v2.x + m3 * v3.x;
        ay += m0 * v0.y + m1 * v1.y + m2 * v2.y + m3 * v3.y;
        az += m0 * v0.z + m1 * v1.z + m2 * v2.z + m3 * v3.z;
        aw += m0 * v0.w + m1 * v1.w + m2 * v2.w + m3 * v3.w;
      }
      ax += __shfl_xor(ax, 8);  ax += __shfl_xor(ax, 16);
      ay += __shfl_xor(ay, 8);  ay += __shfl_xor(ay, 16);
      az += __shfl_xor(az, 8);  az += __shfl_xor(az, 16);
      aw += __shfl_xor(aw, 8);  aw += __shfl_xor(aw, 16);
      if (k < 8) {
        float4* sp = reinterpret_cast<float4*>(&sacc[d * IN_CH + 4 * k]);
        float4 s = *sp;
        s.x += ax; s.y += ay; s.z += az; s.w += aw;
        *sp = s;                         // owner-exclusive, plain RMW
      }
    }
    __syncthreads();
  }

  // ===================== fused epilogue (k_out replacement) =================
  float* xs = reinterpret_cast<float*>(svalu);     // 128 x 32 x-row panel
  float* sinv = reinterpret_cast<float*>(hcnt);
  {
    float4* xs4 = reinterpret_cast<float4*>(xs);
#pragma unroll
    for (int r = 0; r < 2; ++r) {
      int i = t + 512 * r;              // [0,1024): node-local row i>>3, slot i&7
      int node = node0 + (i >> 3);
      float4 v = make_float4(0.f, 0.f, 0.f, 0.f);
      if (node < n) v = x4[node * 8 + (i & 7)];
      xs4[i] = v;
    }
  }
  if (t < BW) sinv[t] = 1.0f / fmaxf((float)sdeg[t], 1.0f);
  __syncthreads();

  const int c0 = k << 2;                // channels [4k, 4k+4)
  const float4 bias = *reinterpret_cast<const float4*>(bl + c0);
  float4 acc[8];
#pragma unroll
  for (int dd = 0; dd < 8; ++dd) acc[dd] = bias;
  const float4* wsb4 = reinterpret_cast<const float4*>(wsb);

  // GEMM1: acc += x-row . Wr^T  (wsb holds Wr-transposed)
  for (int k4 = 0; k4 < 8; ++k4) {
    float4 w0 = wsb4[((4 * k4 + 0) * 128 + c0) >> 2];
    float4 w1 = wsb4[((4 * k4 + 1) * 128 + c0) >> 2];
    float4 w2 = wsb4[((4 * k4 + 2) * 128 + c0) >> 2];
    float4 w3 = wsb4[((4 * k4 + 3) * 128 + c0) >> 2];
#pragma unroll
    for (int dd = 0; dd < 8; ++dd) {
      const int d = (sub << 3) + dd;
      float4 v = *reinterpret_cast<const float4*>(&xs[d * IN_CH + 4 * k4]);
      acc[dd].x += v.x * w0.x + v.y * w1.x + v.z * w2.x + v.w * w3.x;
      acc[dd].y += v.x * w0.y + v.y * w1.y + v.z * w2.y + v.w * w3.y;
      acc[dd].z += v.x * w0.z + v.y * w1.z + v.z * w2.z + v.w * w3.z;
      acc[dd].w += v.x * w0.w + v.y * w1.w + v.z * w2.w + v.w * w3.w;
    }
  }
  __syncthreads();
  // restage wsb <- Wl-transposed; concurrently prescale sacc to the mean
  {
    const float4* wl4 = reinterpret_cast<const float4*>(Wl);
#pragma unroll
    for (int r = 0; r < 2; ++r) {
      int i = t + 512 * r;
      int c = i >> 3;
      int k0 = (i & 7) << 2;
      float4 a = wl4[i];
      wsb[(k0 + 0) * 128 + c] = a.x;
      wsb[(k0 + 1) * 128 + c] = a.y;
      wsb[(k0 + 2) * 128 + c] = a.z;
      wsb[(k0 + 3) * 128 + c] = a.w;
    }
#pragma unroll
    for (int i = 0; i < 8; ++i) {
      int idx = t + 512 * i;
      sacc[idx] *= sinv[idx >> 5];
    }
  }
  __syncthreads();
  // GEMM2: acc += mean-agg . Wl^T; store
  for (int k4 = 0; k4 < 8; ++k4) {
    float4 w0 = wsb4[((4 * k4 + 0) * 128 + c0) >> 2];
    float4 w1 = wsb4[((4 * k4 + 1) * 128 + c0) >> 2];
    float4 w2 = wsb4[((4 * k4 + 2) * 128 + c0) >> 2];
    float4 w3 = wsb4[((4 * k4 + 3) * 128 + c0) >> 2];
#pragma unroll
    for (int dd = 0; dd < 8; ++dd) {
      const int d = (sub << 3) + dd;
      float4 v = *reinterpret_cast<const float4*>(&sacc[d * IN_CH + 4 * k4]);
      acc[dd].x += v.x * w0.x + v.y * w1.x + v.z * w2.x + v.w * w3.x;
      acc[dd].y += v.x * w0.y + v.y * w1.y + v.z * w2.y + v.w * w3.y;
      acc[dd].z += v.x * w0.z + v.y * w1.z + v.z * w2.z + v.w * w3.z;
      acc[dd].w += v.x * w0.w + v.y * w1.w + v.z * w2.w + v.w * w3.w;
    }
  }
#pragma unroll
  for (int dd = 0; dd < 8; ++dd) {
    const int node = node0 + (sub << 3) + dd;
    if (node < n)
      *reinterpret_cast<float4*>(out + (size_t)node * OUT_CH + c0) = acc[dd];
  }
}

extern "C" void kernel_launch(void* const* d_in, const int* in_sizes, int n_in,
                              void* d_out, int out_size, void* d_ws, size_t ws_size,
                              hipStream_t stream) {
  const float* x  = (const float*)d_in[0];
  const int*   ei = (const int*)d_in[1];   // [2, E] row-major int32
  const float* Wl = (const float*)d_in[2];
  const float* Wr = (const float*)d_in[3];
  const float* bl = (const float*)d_in[4];
  float* out = (float*)d_out;

  const int n_nodes = in_sizes[0] / IN_CH;
  const int n_edges = in_sizes[1] / 2;
  const int* src = ei;
  const int* dst = ei + n_edges;
  const int NB = (n_nodes + BW - 1) >> BSHIFT;   // 782

  // fixed-capacity slab per bucket: >= 2x the mean bucket load, pow2, min 4096
  int cap = 4096;
  const int mean2 = (int)(2 * ((long long)n_edges / (NB > 0 ? NB : 1)));
  while (cap < mean2) cap <<= 1;

  char* ws = (char*)d_ws;
  auto align16 = [](size_t v) { return (v + 15) & ~(size_t)15; };
  int* gcursor   = (int*)ws;       ws += align16(NB_P * 4);
  unsigned* part = (unsigned*)ws;  ws += align16((size_t)NB_P * cap * 4);

  k_init<<<(NB_P + 511) / 512, 512, 0, stream>>>(gcursor, cap);
  k_partition<<<(n_edges + PCHUNK - 1) / PCHUNK, 256, 0, stream>>>(
      src, dst, gcursor, part, n_edges);
  k_agg<<<NB, 512, 0, stream>>>(x, part, gcursor, Wl, Wr, bl, out,
                                n_nodes, cap);
}